// Round 6
// baseline (217.659 us; speedup 1.0000x reference)
//
#include <hip/hip_runtime.h>
#include <hip/hip_bf16.h>

// ReparamEmbeddings: V_ORIG=32000, V_NEW=8000, D=1024, R=16, N=16384
// indices: int32 [N], index_map: int32 [V_NEW]
// emb_weight: f32 [V_ORIG, D], down: f32 [V_NEW, D, R], up: f32 [V_NEW, R, D]
// out: f32 [N, 1, D]
//
// Dedup via linked list (head[v]/next[n], atomicExch). Main kernel: ONE WAVE
// per touched vocab entry -- no LDS, no __syncthreads, low VGPR, so occupancy
// (TLP) hides latency instead of register-staged ILP (which cost 2 waves/SIMD
// in the previous round).

#define DDIM 1024
#define RDIM 16

__global__ __launch_bounds__(256) void init_head_kernel(int* __restrict__ head, int V) {
    int v = blockIdx.x * 256 + threadIdx.x;
    if (v < V) head[v] = -1;
}

__global__ __launch_bounds__(256) void link_kernel(const int* __restrict__ idx,
                                                   int* __restrict__ head,
                                                   int* __restrict__ next, int n) {
    int i = blockIdx.x * 256 + threadIdx.x;
    if (i < n) next[i] = atomicExch(&head[idx[i]], i);
}

static __device__ __forceinline__ float4 sel4(bool c, float4 a, float4 b) {
    float4 r;
    r.x = c ? a.x : b.x;
    r.y = c ? a.y : b.y;
    r.z = c ? a.z : b.z;
    r.w = c ? a.w : b.w;
    return r;
}

// One wave per vocab entry v (4 waves/block, fully independent).
// Lane layout, phase 1: c0 = lane&3 owns r-quad [4*c0, 4*c0+4);
//   dgrp = lane>>2 in [0,16); d = dgrp + 16k, k=0..63.
//   down load byte addr = lane*16 + k*1024  -> contiguous 1KB per wave instr.
// Reduce over the 16 lanes of each class with xor masks 4,8,16,32, then
// redistribute the 4 class-quads to every lane via 12 shuffles + selects.
// Phase 2: lane owns d = qd*256 + lane*4 (qd=0..3); up rows are wave-uniform,
//   loads fully coalesced. Write the finished row to every chain slot.
__global__ __launch_bounds__(256) void fused_wave_kernel(
    const int* __restrict__ index_map,
    const float* __restrict__ emb,
    const float* __restrict__ down,
    const float* __restrict__ up,
    const int* __restrict__ head,
    const int* __restrict__ next,
    float* __restrict__ out, int V)
{
    const int lane = threadIdx.x & 63;
    const int v    = (blockIdx.x << 2) | (threadIdx.x >> 6);
    if (v >= V) return;
    const int n0 = head[v];
    if (n0 < 0) return;                      // untouched vocab entry

    const float* __restrict__ e  = emb  + (size_t)index_map[v] * DDIM;
    const float* __restrict__ dn = down + (size_t)v * (DDIM * RDIM);
    const float* __restrict__ u  = up   + (size_t)v * (RDIM * DDIM);

    const int c0   = lane & 3;
    const int dgrp = lane >> 2;

    // ---- Phase 1: partial h for this lane's r-quad ----
    float4 hp = make_float4(0.f, 0.f, 0.f, 0.f);
    #pragma unroll 8
    for (int k = 0; k < 64; ++k) {
        const int d = dgrp + (k << 4);
        const float ed = e[d];                               // one 64B line / instr
        const float4 dq = *(const float4*)(dn + (size_t)d * RDIM + (c0 << 2));
        hp.x += ed * dq.x;
        hp.y += ed * dq.y;
        hp.z += ed * dq.z;
        hp.w += ed * dq.w;
    }

    // ---- Reduce within each class (16 lanes apart by 4) ----
    #pragma unroll
    for (int m = 4; m < 64; m <<= 1) {
        hp.x += __shfl_xor(hp.x, m, 64);
        hp.y += __shfl_xor(hp.y, m, 64);
        hp.z += __shfl_xor(hp.z, m, 64);
        hp.w += __shfl_xor(hp.w, m, 64);
    }

    // ---- Redistribute: every lane gets all four class-quads q0..q3 ----
    float4 t1;
    t1.x = __shfl_xor(hp.x, 1, 64);
    t1.y = __shfl_xor(hp.y, 1, 64);
    t1.z = __shfl_xor(hp.z, 1, 64);
    t1.w = __shfl_xor(hp.w, 1, 64);
    const bool odd = (c0 & 1) != 0;
    float4 pe = sel4(odd, t1, hp);           // class c0 & ~1
    float4 po = sel4(odd, hp, t1);           // class c0 |  1
    float4 pe2, po2;
    pe2.x = __shfl_xor(pe.x, 2, 64);
    pe2.y = __shfl_xor(pe.y, 2, 64);
    pe2.z = __shfl_xor(pe.z, 2, 64);
    pe2.w = __shfl_xor(pe.w, 2, 64);
    po2.x = __shfl_xor(po.x, 2, 64);
    po2.y = __shfl_xor(po.y, 2, 64);
    po2.z = __shfl_xor(po.z, 2, 64);
    po2.w = __shfl_xor(po.w, 2, 64);
    const bool hi = (c0 & 2) != 0;
    const float4 q0 = sel4(hi, pe2, pe);     // h[0..3]
    const float4 q2 = sel4(hi, pe, pe2);     // h[8..11]
    const float4 q1 = sel4(hi, po2, po);     // h[4..7]
    const float4 q3 = sel4(hi, po, po2);     // h[12..15]

    // ---- Phase 2: out[d] = sum_r h[r] * up[r][d] ----
    float4 a0 = make_float4(0.f, 0.f, 0.f, 0.f);
    float4 a1 = a0, a2 = a0, a3 = a0;
    #pragma unroll
    for (int j = 0; j < 4; ++j) {
        const float4 qj = (j == 0) ? q0 : (j == 1) ? q1 : (j == 2) ? q2 : q3;
        #pragma unroll
        for (int t = 0; t < 4; ++t) {
            const float hf = (t == 0) ? qj.x : (t == 1) ? qj.y : (t == 2) ? qj.z : qj.w;
            const float* __restrict__ ur = u + (size_t)(j * 4 + t) * DDIM + (lane << 2);
            const float4 u0 = *(const float4*)(ur + 0);
            const float4 u1 = *(const float4*)(ur + 256);
            const float4 u2 = *(const float4*)(ur + 512);
            const float4 u3 = *(const float4*)(ur + 768);
            a0.x += hf * u0.x; a0.y += hf * u0.y; a0.z += hf * u0.z; a0.w += hf * u0.w;
            a1.x += hf * u1.x; a1.y += hf * u1.y; a1.z += hf * u1.z; a1.w += hf * u1.w;
            a2.x += hf * u2.x; a2.y += hf * u2.y; a2.z += hf * u2.z; a2.w += hf * u2.w;
            a3.x += hf * u3.x; a3.y += hf * u3.y; a3.z += hf * u3.z; a3.w += hf * u3.w;
        }
    }

    // ---- Write the row to every output slot referencing v ----
    int n = n0;
    while (n >= 0) {
        float* o = out + (size_t)n * DDIM + (lane << 2);
        *(float4*)(o + 0)   = a0;
        *(float4*)(o + 256) = a1;
        *(float4*)(o + 512) = a2;
        *(float4*)(o + 768) = a3;
        n = next[n];                          // wave-uniform broadcast load
    }
}

// Fallback (no ws): compute each lookup independently, same wave structure.
__global__ __launch_bounds__(256) void rows_direct_kernel(
    const int* __restrict__ indices,
    const int* __restrict__ index_map,
    const float* __restrict__ emb,
    const float* __restrict__ down,
    const float* __restrict__ up,
    float* __restrict__ out, int N)
{
    const int lane = threadIdx.x & 63;
    const int nn   = (blockIdx.x << 2) | (threadIdx.x >> 6);
    if (nn >= N) return;
    const int v = indices[nn];

    const float* __restrict__ e  = emb  + (size_t)index_map[v] * DDIM;
    const float* __restrict__ dn = down + (size_t)v * (DDIM * RDIM);
    const float* __restrict__ u  = up   + (size_t)v * (RDIM * DDIM);

    const int c0   = lane & 3;
    const int dgrp = lane >> 2;

    float4 hp = make_float4(0.f, 0.f, 0.f, 0.f);
    #pragma unroll 8
    for (int k = 0; k < 64; ++k) {
        const int d = dgrp + (k << 4);
        const float ed = e[d];
        const float4 dq = *(const float4*)(dn + (size_t)d * RDIM + (c0 << 2));
        hp.x += ed * dq.x; hp.y += ed * dq.y; hp.z += ed * dq.z; hp.w += ed * dq.w;
    }
    #pragma unroll
    for (int m = 4; m < 64; m <<= 1) {
        hp.x += __shfl_xor(hp.x, m, 64);
        hp.y += __shfl_xor(hp.y, m, 64);
        hp.z += __shfl_xor(hp.z, m, 64);
        hp.w += __shfl_xor(hp.w, m, 64);
    }
    float4 t1;
    t1.x = __shfl_xor(hp.x, 1, 64);
    t1.y = __shfl_xor(hp.y, 1, 64);
    t1.z = __shfl_xor(hp.z, 1, 64);
    t1.w = __shfl_xor(hp.w, 1, 64);
    const bool odd = (c0 & 1) != 0;
    float4 pe = sel4(odd, t1, hp);
    float4 po = sel4(odd, hp, t1);
    float4 pe2, po2;
    pe2.x = __shfl_xor(pe.x, 2, 64);
    pe2.y = __shfl_xor(pe.y, 2, 64);
    pe2.z = __shfl_xor(pe.z, 2, 64);
    pe2.w = __shfl_xor(pe.w, 2, 64);
    po2.x = __shfl_xor(po.x, 2, 64);
    po2.y = __shfl_xor(po.y, 2, 64);
    po2.z = __shfl_xor(po.z, 2, 64);
    po2.w = __shfl_xor(po.w, 2, 64);
    const bool hi = (c0 & 2) != 0;
    const float4 q0 = sel4(hi, pe2, pe);
    const float4 q2 = sel4(hi, pe, pe2);
    const float4 q1 = sel4(hi, po2, po);
    const float4 q3 = sel4(hi, po, po2);

    float4 a0 = make_float4(0.f, 0.f, 0.f, 0.f);
    float4 a1 = a0, a2 = a0, a3 = a0;
    #pragma unroll
    for (int j = 0; j < 4; ++j) {
        const float4 qj = (j == 0) ? q0 : (j == 1) ? q1 : (j == 2) ? q2 : q3;
        #pragma unroll
        for (int t = 0; t < 4; ++t) {
            const float hf = (t == 0) ? qj.x : (t == 1) ? qj.y : (t == 2) ? qj.z : qj.w;
            const float* __restrict__ ur = u + (size_t)(j * 4 + t) * DDIM + (lane << 2);
            const float4 u0 = *(const float4*)(ur + 0);
            const float4 u1 = *(const float4*)(ur + 256);
            const float4 u2 = *(const float4*)(ur + 512);
            const float4 u3 = *(const float4*)(ur + 768);
            a0.x += hf * u0.x; a0.y += hf * u0.y; a0.z += hf * u0.z; a0.w += hf * u0.w;
            a1.x += hf * u1.x; a1.y += hf * u1.y; a1.z += hf * u1.z; a1.w += hf * u1.w;
            a2.x += hf * u2.x; a2.y += hf * u2.y; a2.z += hf * u2.z; a2.w += hf * u2.w;
            a3.x += hf * u3.x; a3.y += hf * u3.y; a3.z += hf * u3.z; a3.w += hf * u3.w;
        }
    }
    float* o = out + (size_t)nn * DDIM + (lane << 2);
    *(float4*)(o + 0)   = a0;
    *(float4*)(o + 256) = a1;
    *(float4*)(o + 512) = a2;
    *(float4*)(o + 768) = a3;
}

extern "C" void kernel_launch(void* const* d_in, const int* in_sizes, int n_in,
                              void* d_out, int out_size, void* d_ws, size_t ws_size,
                              hipStream_t stream)
{
    const int*   indices   = (const int*)d_in[0];
    const int*   index_map = (const int*)d_in[1];
    const float* emb       = (const float*)d_in[2];
    const float* down      = (const float*)d_in[3];
    const float* up        = (const float*)d_in[4];
    float*       out       = (float*)d_out;

    const int N = in_sizes[0];
    const int V = in_sizes[1];

    // ws layout: head[V] | next[N]
    const size_t ws_need = (size_t)(V + N) * sizeof(int);

    if (ws_size >= ws_need) {
        int* head = (int*)d_ws;
        int* next = head + V;
        init_head_kernel<<<(V + 255) / 256, 256, 0, stream>>>(head, V);
        link_kernel<<<(N + 255) / 256, 256, 0, stream>>>(indices, head, next, N);
        fused_wave_kernel<<<(V + 3) / 4, 256, 0, stream>>>(index_map, emb, down, up,
                                                           head, next, out, V);
    } else {
        rows_direct_kernel<<<(N + 3) / 4, 256, 0, stream>>>(indices, index_map, emb,
                                                            down, up, out, N);
    }
}

// Round 7
// 192.383 us; speedup vs baseline: 1.1314x; 1.1314x over previous
//
#include <hip/hip_runtime.h>
#include <hip/hip_bf16.h>

// ReparamEmbeddings: V_ORIG=32000, V_NEW=8000, D=1024, R=16, N=16384
// indices: int32 [N], index_map: int32 [V_NEW]
// emb_weight: f32 [V_ORIG, D], down: f32 [V_NEW, D, R], up: f32 [V_NEW, R, D]
// out: f32 [N, 1, D]
//
// Dedup via linked list + first-touch worklist. One wave per touched vocab
// entry (grid-stride over the worklist). Factor streams (down/up) and output
// writes use NONTEMPORAL ops (zero reuse -> bypass cache allocation). The
// 4KB e row is staged in LDS so phase 1 is a single sequential down-stream.

#define DDIM 1024
#define RDIM 16

typedef float v4f __attribute__((ext_vector_type(4)));

static __device__ __forceinline__ v4f ldnt(const float* p) {
    return __builtin_nontemporal_load((const v4f*)p);
}
static __device__ __forceinline__ void stnt(float* p, v4f v) {
    __builtin_nontemporal_store(v, (v4f*)p);
}
static __device__ __forceinline__ v4f sel4(bool c, v4f a, v4f b) {
    v4f r;
    r[0] = c ? a[0] : b[0];
    r[1] = c ? a[1] : b[1];
    r[2] = c ? a[2] : b[2];
    r[3] = c ? a[3] : b[3];
    return r;
}

// init: head[v] = -1, nwork = 0
__global__ __launch_bounds__(256) void init_kernel(int* __restrict__ head, int* __restrict__ nwork, int V) {
    int i = blockIdx.x * 256 + threadIdx.x;
    if (i < V) head[i] = -1;
    if (i == 0) *nwork = 0;
}

// link: next[i] = old head; first toucher of v appends v to the worklist.
__global__ __launch_bounds__(256) void link_kernel(const int* __restrict__ idx,
                                                   int* __restrict__ head,
                                                   int* __restrict__ next,
                                                   int* __restrict__ work,
                                                   int* __restrict__ nwork, int n) {
    int i = blockIdx.x * 256 + threadIdx.x;
    if (i < n) {
        int v = idx[i];
        int old = atomicExch(&head[v], i);
        next[i] = old;
        if (old < 0) work[atomicAdd(nwork, 1)] = v;
    }
}

// Shared math: compute the row for vocab entry v into a0..a3.
// Lane layout phase 1: c0=lane&3 owns r-quad [4c0,4c0+4); dgrp=lane>>2;
//   d = dgrp + 16k; down byte addr = lane*16 + k*1024 (contiguous 1KB/instr).
// Butterfly masks 4..32 reduce each class; 12-shuffle ladder redistributes
// all 16 h values to every lane. Phase 2: lane owns d = q*256 + lane*4.
static __device__ __forceinline__ void compute_row(
    const float* __restrict__ e_lds,     // staged e row (LDS, 1024 floats)
    const float* __restrict__ dn,        // down[v], 64KB
    const float* __restrict__ u,         // up[v], 64KB
    int lane, v4f& a0, v4f& a1, v4f& a2, v4f& a3)
{
    const int c0   = lane & 3;
    const int dgrp = lane >> 2;

    // ---- Phase 1: pure sequential NT stream of down[v] ----
    v4f hp = {0.f, 0.f, 0.f, 0.f};
    const float* dnb = dn + (dgrp << 4) + (c0 << 2);
    #pragma unroll 8
    for (int k = 0; k < 64; ++k) {
        const float ed = e_lds[(k << 4) + dgrp];      // broadcast ds_read
        const v4f dq = ldnt(dnb + (k << 8));
        hp += ed * dq;
    }

    // ---- Reduce within each class (lanes 4 apart) ----
    #pragma unroll
    for (int m = 4; m < 64; m <<= 1) {
        v4f t;
        t[0] = __shfl_xor(hp[0], m, 64);
        t[1] = __shfl_xor(hp[1], m, 64);
        t[2] = __shfl_xor(hp[2], m, 64);
        t[3] = __shfl_xor(hp[3], m, 64);
        hp += t;
    }

    // ---- Redistribute all four class-quads to every lane ----
    v4f t1;
    t1[0] = __shfl_xor(hp[0], 1, 64);
    t1[1] = __shfl_xor(hp[1], 1, 64);
    t1[2] = __shfl_xor(hp[2], 1, 64);
    t1[3] = __shfl_xor(hp[3], 1, 64);
    const bool odd = (c0 & 1) != 0;
    v4f pe = sel4(odd, t1, hp);                       // class c0 & ~1
    v4f po = sel4(odd, hp, t1);                       // class c0 |  1
    v4f pe2, po2;
    pe2[0] = __shfl_xor(pe[0], 2, 64);
    pe2[1] = __shfl_xor(pe[1], 2, 64);
    pe2[2] = __shfl_xor(pe[2], 2, 64);
    pe2[3] = __shfl_xor(pe[3], 2, 64);
    po2[0] = __shfl_xor(po[0], 2, 64);
    po2[1] = __shfl_xor(po[1], 2, 64);
    po2[2] = __shfl_xor(po[2], 2, 64);
    po2[3] = __shfl_xor(po[3], 2, 64);
    const bool hi = (c0 & 2) != 0;
    const v4f q0 = sel4(hi, pe2, pe);                 // h[0..3]
    const v4f q2 = sel4(hi, pe, pe2);                 // h[8..11]
    const v4f q1 = sel4(hi, po2, po);                 // h[4..7]
    const v4f q3 = sel4(hi, po, po2);                 // h[12..15]

    float hh[16];
    #pragma unroll
    for (int i = 0; i < 4; ++i) {
        hh[i]      = q0[i];
        hh[4 + i]  = q1[i];
        hh[8 + i]  = q2[i];
        hh[12 + i] = q3[i];
    }

    // ---- Phase 2: sequential NT stream of up[v] ----
    a0 = (v4f){0.f, 0.f, 0.f, 0.f};
    a1 = a0; a2 = a0; a3 = a0;
    const float* ub = u + (lane << 2);
    #pragma unroll 4
    for (int r = 0; r < RDIM; ++r) {
        const float* ur = ub + (r << 10);
        const v4f u0 = ldnt(ur + 0);
        const v4f u1 = ldnt(ur + 256);
        const v4f u2 = ldnt(ur + 512);
        const v4f u3 = ldnt(ur + 768);
        const float hf = hh[r];
        a0 += hf * u0;
        a1 += hf * u1;
        a2 += hf * u2;
        a3 += hf * u3;
    }
}

// One wave per worklist item; 1024 blocks x 4 waves grid-stride the worklist.
__global__ __launch_bounds__(256) void fused_wave_kernel(
    const int* __restrict__ index_map,
    const float* __restrict__ emb,
    const float* __restrict__ down,
    const float* __restrict__ up,
    const int* __restrict__ head,
    const int* __restrict__ next,
    const int* __restrict__ work,
    const int* __restrict__ nwork,
    float* __restrict__ out)
{
    __shared__ v4f els4[4][DDIM / 4];
    const int lane = threadIdx.x & 63;
    const int wib  = threadIdx.x >> 6;
    const int nw   = *nwork;
    const int stride = gridDim.x << 2;

    for (int wi = (blockIdx.x << 2) + wib; wi < nw; wi += stride) {
        const int v = work[wi];

        // Stage e row (4KB) into this wave's LDS slice (cached loads: emb
        // rows can be shared across vocab entries via index_map collisions).
        const v4f* e4 = (const v4f*)(emb + (size_t)index_map[v] * DDIM);
        els4[wib][lane]       = e4[lane];
        els4[wib][lane + 64]  = e4[lane + 64];
        els4[wib][lane + 128] = e4[lane + 128];
        els4[wib][lane + 192] = e4[lane + 192];
        const float* e_lds = (const float*)&els4[wib][0];

        v4f a0, a1, a2, a3;
        compute_row(e_lds,
                    down + (size_t)v * (DDIM * RDIM),
                    up   + (size_t)v * (RDIM * DDIM),
                    lane, a0, a1, a2, a3);

        // Write the row to every output slot referencing v (NT stores).
        int n = head[v];
        while (n >= 0) {
            float* o = out + (size_t)n * DDIM + (lane << 2);
            stnt(o + 0,   a0);
            stnt(o + 256, a1);
            stnt(o + 512, a2);
            stnt(o + 768, a3);
            n = next[n];                      // wave-uniform broadcast load
        }
    }
}

// Fallback (tiny ws): one wave per lookup, same math, no dedup.
__global__ __launch_bounds__(256) void rows_direct_kernel(
    const int* __restrict__ indices,
    const int* __restrict__ index_map,
    const float* __restrict__ emb,
    const float* __restrict__ down,
    const float* __restrict__ up,
    float* __restrict__ out, int N)
{
    __shared__ v4f els4[4][DDIM / 4];
    const int lane = threadIdx.x & 63;
    const int wib  = threadIdx.x >> 6;
    const int nn   = (blockIdx.x << 2) | wib;
    if (nn >= N) return;
    const int v = indices[nn];

    const v4f* e4 = (const v4f*)(emb + (size_t)index_map[v] * DDIM);
    els4[wib][lane]       = e4[lane];
    els4[wib][lane + 64]  = e4[lane + 64];
    els4[wib][lane + 128] = e4[lane + 128];
    els4[wib][lane + 192] = e4[lane + 192];
    const float* e_lds = (const float*)&els4[wib][0];

    v4f a0, a1, a2, a3;
    compute_row(e_lds,
                down + (size_t)v * (DDIM * RDIM),
                up   + (size_t)v * (RDIM * DDIM),
                lane, a0, a1, a2, a3);

    float* o = out + (size_t)nn * DDIM + (lane << 2);
    stnt(o + 0,   a0);
    stnt(o + 256, a1);
    stnt(o + 512, a2);
    stnt(o + 768, a3);
}

extern "C" void kernel_launch(void* const* d_in, const int* in_sizes, int n_in,
                              void* d_out, int out_size, void* d_ws, size_t ws_size,
                              hipStream_t stream)
{
    const int*   indices   = (const int*)d_in[0];
    const int*   index_map = (const int*)d_in[1];
    const float* emb       = (const float*)d_in[2];
    const float* down      = (const float*)d_in[3];
    const float* up        = (const float*)d_in[4];
    float*       out       = (float*)d_out;

    const int N = in_sizes[0];
    const int V = in_sizes[1];

    // ws layout: head[V] | next[N] | work[V] | nwork[1]
    const size_t ws_need = (size_t)(2 * V + N + 1) * sizeof(int);

    if (ws_size >= ws_need) {
        int* head  = (int*)d_ws;
        int* next  = head + V;
        int* work  = next + N;
        int* nwork = work + V;
        init_kernel<<<(V + 255) / 256, 256, 0, stream>>>(head, nwork, V);
        link_kernel<<<(N + 255) / 256, 256, 0, stream>>>(indices, head, next, work, nwork, N);
        fused_wave_kernel<<<1024, 256, 0, stream>>>(index_map, emb, down, up,
                                                    head, next, work, nwork, out);
    } else {
        rows_direct_kernel<<<(N + 3) / 4, 256, 0, stream>>>(indices, index_map, emb,
                                                            down, up, out, N);
    }
}